// Round 2
// baseline (13.801 us; speedup 1.0000x reference)
//
#include <hip/hip_runtime.h>
#include <hip/hip_bf16.h>

// labels[b,l,i] = argmin_j ( tn[b,l,i] - cbn[i,j] )  with tn constant over j
//               = argmax_j cbn[i,j] = argmax_j codebook[i,j]   (positive affine map
//                 preserves argmax and first-occurrence tie-break).
// => output = per-row argmax of the 64x64 codebook, broadcast over all B*L rows.
//
// Wave-autonomous version: lane l computes argmax of codebook row l (one wave
// covers all 64 rows), then __shfl-gathers the 4 labels its int4 store needs.
// No LDS, no __syncthreads, no idle lanes.

#define Q_DIM 64

__global__ __launch_bounds__(256) void bestrq_labels_kernel(
    const float* __restrict__ codebook,  // (C=64, Q=64) f32
    int* __restrict__ out,               // (B*L, C) int32, flat
    int total4)                          // B*L*C / 4
{
    const int t = threadIdx.x;
    const int lane = t & 63;

    // Argmax of row `lane`, vectorized: 16 x float4 (L1-hot after first wave).
    const float4* row = reinterpret_cast<const float4*>(codebook + lane * Q_DIM);
    float4 v0 = row[0];
    float best = v0.x; int bj = 0;
    if (v0.y > best) { best = v0.y; bj = 1; }   // strict > keeps FIRST max
    if (v0.z > best) { best = v0.z; bj = 2; }
    if (v0.w > best) { best = v0.w; bj = 3; }
#pragma unroll
    for (int j4 = 1; j4 < 16; ++j4) {
        float4 v = row[j4];
        const int base = j4 * 4;
        if (v.x > best) { best = v.x; bj = base;     }
        if (v.y > best) { best = v.y; bj = base + 1; }
        if (v.z > best) { best = v.z; bj = base + 2; }
        if (v.w > best) { best = v.w; bj = base + 3; }
    }

    // This thread's int4 store covers output columns 4c..4c+3, c = (global p) & 15.
    // Per-wave global base ≡ 0 (mod 16) and the grid stride is a multiple of 16,
    // so c == lane & 15, constant across stride iterations.
    const int c = lane & 15;
    int4 lab;
    lab.x = __shfl(bj, 4 * c + 0);
    lab.y = __shfl(bj, 4 * c + 1);
    lab.z = __shfl(bj, 4 * c + 2);
    lab.w = __shfl(bj, 4 * c + 3);

    int4* o4 = reinterpret_cast<int4*>(out);
    for (int p = blockIdx.x * blockDim.x + t; p < total4; p += gridDim.x * blockDim.x) {
        o4[p] = lab;
    }
}

extern "C" void kernel_launch(void* const* d_in, const int* in_sizes, int n_in,
                              void* d_out, int out_size, void* d_ws, size_t ws_size,
                              hipStream_t stream) {
    // inputs: d_in[0]=x (unused), d_in[1]=W (unused), d_in[2]=codebook (64*64 f32)
    const float* codebook = (const float*)d_in[2];
    int* out = (int*)d_out;

    const int total4 = out_size / 4;              // 1,048,576 / 4 = 262,144
    const int block = 256;
    int grid = (total4 + block - 1) / block;      // 1024 blocks -> 1 int4/thread
    if (grid > 2048) grid = 2048;

    bestrq_labels_kernel<<<grid, block, 0, stream>>>(codebook, out, total4);
}

// Round 3
// 11.629 us; speedup vs baseline: 1.1868x; 1.1868x over previous
//
#include <hip/hip_runtime.h>
#include <hip/hip_bf16.h>

// labels[b,l,i] = argmin_j ( tn[b,l,i] - cbn[i,j] )  with tn constant over j
//               = argmax_j cbn[i,j] = argmax_j codebook[i,j]   (positive affine map
//                 preserves argmax and first-occurrence tie-break).
// => output = per-row argmax of the 64x64 codebook, broadcast over all B*L rows.
//
// Two-dispatch split: A computes the 64 labels ONCE into d_ws; B is a pure
// pattern-fill (1 int4 load from L2-hot ws + 1 int4 store per thread).

#define Q_DIM 64

__global__ __launch_bounds__(64) void bestrq_argmax_kernel(
    const float* __restrict__ codebook,  // (64, 64) f32
    int* __restrict__ ws)                // 64 ints out
{
    const int lane = threadIdx.x;  // one wave: lane l handles row l
    const float4* row = reinterpret_cast<const float4*>(codebook + lane * Q_DIM);
    float4 v0 = row[0];
    float best = v0.x; int bj = 0;
    if (v0.y > best) { best = v0.y; bj = 1; }   // strict > keeps FIRST max
    if (v0.z > best) { best = v0.z; bj = 2; }
    if (v0.w > best) { best = v0.w; bj = 3; }
#pragma unroll
    for (int j4 = 1; j4 < 16; ++j4) {
        float4 v = row[j4];
        const int base = j4 * 4;
        if (v.x > best) { best = v.x; bj = base;     }
        if (v.y > best) { best = v.y; bj = base + 1; }
        if (v.z > best) { best = v.z; bj = base + 2; }
        if (v.w > best) { best = v.w; bj = base + 3; }
    }
    ws[lane] = bj;
}

__global__ __launch_bounds__(256) void bestrq_fill_kernel(
    const int4* __restrict__ ws4,  // 16 x int4 label pattern
    int4* __restrict__ o4)         // output, exact-cover grid
{
    const int p = blockIdx.x * 256 + threadIdx.x;
    o4[p] = ws4[p & 15];   // same 256 B for all threads -> L1 broadcast
}

extern "C" void kernel_launch(void* const* d_in, const int* in_sizes, int n_in,
                              void* d_out, int out_size, void* d_ws, size_t ws_size,
                              hipStream_t stream) {
    // inputs: d_in[0]=x (unused), d_in[1]=W (unused), d_in[2]=codebook (64*64 f32)
    const float* codebook = (const float*)d_in[2];
    int* ws = (int*)d_ws;
    int4* o4 = (int4*)d_out;

    bestrq_argmax_kernel<<<1, 64, 0, stream>>>(codebook, ws);

    const int total4 = out_size / 4;          // 262,144
    const int grid = total4 / 256;            // 1024 blocks, exact cover
    bestrq_fill_kernel<<<grid, 256, 0, stream>>>((const int4*)ws, o4);
}

// Round 4
// 11.309 us; speedup vs baseline: 1.2204x; 1.0282x over previous
//
#include <hip/hip_runtime.h>
#include <hip/hip_bf16.h>

// labels[b,l,i] = argmin_j ( tn[b,l,i] - cbn[i,j] )  with tn constant over j
//               = argmax_j cbn[i,j] = argmax_j codebook[i,j]   (positive affine map
//                 preserves argmax values-order and exact ties).
// => output = per-row argmax of the 64x64 codebook, broadcast over all B*L rows.
//
// Single dispatch (R3 proved a 2nd dispatch costs ~2us). Prologue parallelized
// over all 256 threads: thread t scans 16 elems of row t>>2 (quarter t&3) with
// float4 loads, then a 2-step shfl_xor reduce over the 4-lane group with exact
// first-occurrence tie-break. 64 LDS writes -> barrier -> 1 int4 store/thread.

__global__ __launch_bounds__(256) void bestrq_labels_kernel(
    const float* __restrict__ codebook,  // (64, 64) f32
    int4* __restrict__ o4)               // (B*L*64)/4 int4, exact-cover grid
{
    __shared__ int lab[64];

    const int t = threadIdx.x;
    const int r = t >> 2;   // row 0..63
    const int s = t & 3;    // 16-element quarter within the row

    const float4* seg = reinterpret_cast<const float4*>(codebook + r * 64 + s * 16);
    float4 a = seg[0], b = seg[1], c = seg[2], d = seg[3];

    // Local argmax over 16 elements; strict > keeps FIRST max within segment.
    float best = a.x; int bj = 0;
    if (a.y > best) { best = a.y; bj = 1;  }
    if (a.z > best) { best = a.z; bj = 2;  }
    if (a.w > best) { best = a.w; bj = 3;  }
    if (b.x > best) { best = b.x; bj = 4;  }
    if (b.y > best) { best = b.y; bj = 5;  }
    if (b.z > best) { best = b.z; bj = 6;  }
    if (b.w > best) { best = b.w; bj = 7;  }
    if (c.x > best) { best = c.x; bj = 8;  }
    if (c.y > best) { best = c.y; bj = 9;  }
    if (c.z > best) { best = c.z; bj = 10; }
    if (c.w > best) { best = c.w; bj = 11; }
    if (d.x > best) { best = d.x; bj = 12; }
    if (d.y > best) { best = d.y; bj = 13; }
    if (d.z > best) { best = d.z; bj = 14; }
    if (d.w > best) { best = d.w; bj = 15; }
    bj += s * 16;   // global column index

    // Reduce across the 4 lanes sharing this row (intra-wave: lanes 4k..4k+3).
    // Exact first-occurrence semantics: greater value wins; equal -> lower idx.
#pragma unroll
    for (int m = 1; m <= 2; m <<= 1) {
        float ov = __shfl_xor(best, m);
        int   oi = __shfl_xor(bj, m);
        if (ov > best || (ov == best && oi < bj)) { best = ov; bj = oi; }
    }

    if (s == 0) lab[r] = bj;
    __syncthreads();

    // p = blockIdx.x*256 + t; 256 % 16 == 0 so chunk = p & 15 = t & 15.
    const int4* lab4 = reinterpret_cast<const int4*>(lab);
    o4[blockIdx.x * 256 + t] = lab4[t & 15];
}

extern "C" void kernel_launch(void* const* d_in, const int* in_sizes, int n_in,
                              void* d_out, int out_size, void* d_ws, size_t ws_size,
                              hipStream_t stream) {
    // inputs: d_in[0]=x (unused), d_in[1]=W (unused), d_in[2]=codebook (64*64 f32)
    const float* codebook = (const float*)d_in[2];
    int4* o4 = (int4*)d_out;

    const int total4 = out_size / 4;   // 262,144
    const int grid = total4 / 256;     // 1024 blocks, exact cover, 1 int4/thread
    bestrq_labels_kernel<<<grid, 256, 0, stream>>>(codebook, o4);
}

// Round 5
// 9.750 us; speedup vs baseline: 1.4156x; 1.1600x over previous
//
#include <hip/hip_runtime.h>
#include <hip/hip_bf16.h>

// labels[b,l,i] = argmin_j ( tn[b,l,i] - cbn[i,j] )  with tn constant over j
//               = argmax_j cbn[i,j] = argmax_j codebook[i,j]   (positive affine map
//                 preserves argmax and first-occurrence tie-break).
// => output is the per-row argmax of the 64x64 codebook, broadcast over B*L.
//
// Byte-identical resubmission of the Round-1 kernel (best measured: 9.78 us)
// as a reproducibility probe: rounds 1-4 spread 9.8-13.8 us across variants
// whose bodies differ by <1 us of theoretical work, so this measures the
// noise band of the dispatch-overhead floor.

#define C_DIM 64
#define Q_DIM 64

__global__ __launch_bounds__(256) void bestrq_labels_kernel(
    const float* __restrict__ codebook,  // (C=64, Q=64) f32
    int* __restrict__ out,               // (B*L, C) int32, flat
    int total4)                          // B*L*C / 4
{
    __shared__ int lab[C_DIM];  // 64 ints = 16 x int4

    const int t = threadIdx.x;
    if (t < C_DIM) {
        // Each of the first 64 threads scans one codebook row (64 floats, L1-hot).
        const float* row = codebook + t * Q_DIM;
        float best = row[0];
        int bj = 0;
#pragma unroll
        for (int j = 1; j < Q_DIM; ++j) {
            float v = row[j];
            if (v > best) { best = v; bj = j; }   // strict > keeps FIRST max == argmin tie-break
        }
        lab[t] = bj;
    }
    __syncthreads();

    const int4* lab4 = reinterpret_cast<const int4*>(lab);
    int4* o4 = reinterpret_cast<int4*>(out);
    // C=64 -> 16 int4 per output row; (p & 15) selects the column chunk.
    for (int p = blockIdx.x * blockDim.x + t; p < total4; p += gridDim.x * blockDim.x) {
        o4[p] = lab4[p & 15];
    }
}

extern "C" void kernel_launch(void* const* d_in, const int* in_sizes, int n_in,
                              void* d_out, int out_size, void* d_ws, size_t ws_size,
                              hipStream_t stream) {
    // inputs: d_in[0]=x (unused), d_in[1]=W (unused), d_in[2]=codebook (64*64 f32)
    const float* codebook = (const float*)d_in[2];
    int* out = (int*)d_out;

    const int total4 = out_size / 4;              // 1,048,576 / 4 = 262,144
    const int block = 256;
    int grid = (total4 + block - 1) / block;      // 1024
    if (grid > 2048) grid = 2048;

    bestrq_labels_kernel<<<grid, block, 0, stream>>>(codebook, out, total4);
}